// Round 7
// baseline (167.318 us; speedup 1.0000x reference)
//
#include <hip/hip_runtime.h>
#include <hip/hip_bf16.h>

#define SQ 2048
#define NH 32
#define DH 128
#define NK 256
#define SCALE 0.08838834764831845f
#define LOG2E 1.4426950408889634f

typedef __attribute__((ext_vector_type(8))) __bf16 bf16x8;
typedef __attribute__((ext_vector_type(4))) float floatx4;

// Compiler-only memory fence: same-wave DS ops execute in order on CDNA, but
// TBAA lets clang reorder uint4 stores vs bf16x8 loads to the same LDS bytes.
// (R6 omitted this -> ds_reads hoisted above staging writes -> NaN.)
#define LDS_FENCE() asm volatile("" ::: "memory")

// element strides (u16)
#define KS_STRIDE 136   // K tile rows: 272B, 16B-aligned
#define VB_STRIDE 72    // V^T rows: 144B, 16B-aligned
#define PB_STRIDE 264
#define WSLOT 4608      // per-wave staging bytes: max(K 16*272=4352, V 32*144=4608)

// LDS: pbuf 16896 + 4*WSLOT 18432 + sink 128 + red 512 + red2 512 = 36480 -> 4 blocks/CU
#define OFF_KV   16896
#define OFF_SINK 35328
#define OFF_RED  35456
#define OFF_RED2 35968
#define SMEM_SZ  36480

__device__ __forceinline__ unsigned pk_bf16(float a, float b) {
  union { __hip_bfloat162 h2; unsigned u; } c;
  c.h2 = __float22bfloat162_rn(make_float2(a, b));
  return c.u;
}

__device__ __forceinline__ float fast_exp2(float x) {
#if __has_builtin(__builtin_amdgcn_exp2f)
  return __builtin_amdgcn_exp2f(x);
#else
  return exp2f(x);
#endif
}

template <int CTRL>
__device__ __forceinline__ float dpp_rot(float x) {
  int i = __builtin_bit_cast(int, x);
  i = __builtin_amdgcn_mov_dpp(i, CTRL, 0xF, 0xF, true);
  return __builtin_bit_cast(float, i);
}
#define RED16_MAX(v) { v = fmaxf(v, dpp_rot<0x121>(v)); v = fmaxf(v, dpp_rot<0x122>(v)); \
                       v = fmaxf(v, dpp_rot<0x124>(v)); v = fmaxf(v, dpp_rot<0x128>(v)); }
#define RED16_SUM(v) { v += dpp_rot<0x121>(v); v += dpp_rot<0x122>(v); \
                       v += dpp_rot<0x124>(v); v += dpp_rot<0x128>(v); }

// ---- pre-pass: kv fp32 [4096][2][128] -> bf16 in d_ws ----
__global__ __launch_bounds__(256) void kv_to_bf16(const float* __restrict__ kv,
                                                  unsigned short* __restrict__ kvb) {
  int i = blockIdx.x * 256 + threadIdx.x;  // float4 index, 262144 total
  float4 f = ((const float4*)kv)[i];
  uint2 o = { pk_bf16(f.x, f.y), pk_bf16(f.z, f.w) };
  ((uint2*)kvb)[i] = o;
}

struct VR { uint4 a, b, c, d; };

// V gather, wave-private: lane (quad,l16) loads keys 4*l16..+3 of chunk c,
// d-range [wave*32+quad*8, +8) (16B contiguous)
__device__ __forceinline__ VR v_load_w(const unsigned short* __restrict__ kvb,
                                       const int* __restrict__ tkg, int c,
                                       int wave, int quad, int l16) {
  int4 i4 = *(const int4*)(tkg + c * 64 + 4 * l16);
  int off = 128 + wave * 32 + quad * 8;
  VR v;
  v.a = *(const uint4*)(kvb + (size_t)i4.x * 256 + off);
  v.b = *(const uint4*)(kvb + (size_t)i4.y * 256 + off);
  v.c = *(const uint4*)(kvb + (size_t)i4.z * 256 + off);
  v.d = *(const uint4*)(kvb + (size_t)i4.w * 256 + off);
  return v;
}

// transpose-pack to own slot: V^T[dloc][klocal], dloc = quad*8+..., klocal = 4*l16..+3
__device__ __forceinline__ void v_write_w(unsigned short* kvw, const VR& v,
                                          int quad, int l16) {
  const unsigned* pa = (const unsigned*)&v.a;
  const unsigned* pb = (const unsigned*)&v.b;
  const unsigned* pc = (const unsigned*)&v.c;
  const unsigned* pd = (const unsigned*)&v.d;
#pragma unroll
  for (int w = 0; w < 4; w++) {
    unsigned lo01 = __builtin_amdgcn_perm(pb[w], pa[w], 0x05040100u);
    unsigned lo23 = __builtin_amdgcn_perm(pd[w], pc[w], 0x05040100u);
    unsigned hi01 = __builtin_amdgcn_perm(pb[w], pa[w], 0x07060302u);
    unsigned hi23 = __builtin_amdgcn_perm(pd[w], pc[w], 0x07060302u);
    uint2 lo = { lo01, lo23 }, hi = { hi01, hi23 };
    int dl = quad * 8 + 2 * w;
    *(uint2*)&kvw[dl * VB_STRIDE + 4 * l16] = lo;
    *(uint2*)&kvw[(dl + 1) * VB_STRIDE + 4 * l16] = hi;
  }
}

// PV chunk: A from pbuf (shared), B from own V^T slot (rows nt*16+l16)
__device__ __forceinline__ void pv_chunk(const unsigned short* pbuf,
                                         const unsigned short* kvw, int c,
                                         int quad, int l16, floatx4 oacc[2][2]) {
#pragma unroll
  for (int ks = 0; ks < 2; ks++) {
    int kof = c * 64 + ks * 32 + quad * 8;
    bf16x8 a0 = *(const bf16x8*)&pbuf[l16 * PB_STRIDE + kof];
    bf16x8 a1 = *(const bf16x8*)&pbuf[(16 + l16) * PB_STRIDE + kof];
    int kl = ks * 32 + quad * 8;
    bf16x8 b0 = *(const bf16x8*)&kvw[l16 * VB_STRIDE + kl];
    bf16x8 b1 = *(const bf16x8*)&kvw[(16 + l16) * VB_STRIDE + kl];
    oacc[0][0] = __builtin_amdgcn_mfma_f32_16x16x32_bf16(a0, b0, oacc[0][0], 0, 0, 0);
    oacc[0][1] = __builtin_amdgcn_mfma_f32_16x16x32_bf16(a0, b1, oacc[0][1], 0, 0, 0);
    oacc[1][0] = __builtin_amdgcn_mfma_f32_16x16x32_bf16(a1, b0, oacc[1][0], 0, 0, 0);
    oacc[1][1] = __builtin_amdgcn_mfma_f32_16x16x32_bf16(a1, b1, oacc[1][1], 0, 0, 0);
  }
}

__global__ __launch_bounds__(256, 4) void sparse_attn_kernel(
    const float* __restrict__ q, const unsigned short* __restrict__ kvb,
    const float* __restrict__ sink, const int* __restrict__ topk,
    float* __restrict__ out) {
  __shared__ __align__(16) char smem[SMEM_SZ];
  unsigned short* pbuf = (unsigned short*)smem;
  float* sink_s = (float*)(smem + OFF_SINK);
  float* red    = (float*)(smem + OFF_RED);
  float* red2   = (float*)(smem + OFF_RED2);

  const int tid = threadIdx.x;
  const int s = blockIdx.x;
  const int wave = tid >> 6;
  const int lane = tid & 63;
  const int quad = lane >> 4;
  const int l16 = lane & 15;
  const int* tkg = topk + (size_t)s * NK;
  const float QSC = SCALE * LOG2E;
  unsigned short* kvw = (unsigned short*)(smem + OFF_KV + wave * WSLOT);  // own slot

  if (tid < 32) sink_s[tid] = sink[tid] * LOG2E;  // read only after red barrier

  // K row indices for this lane's n-rows (wave-private tile rows)
  int kidx[4];
#pragma unroll
  for (int c = 0; c < 4; c++) kidx[c] = tkg[c * 64 + wave * 16 + l16];

  // Q A-fragments direct from global (raw bf16; SCALE folded into softmax)
  bf16x8 afrag[2][4];
#pragma unroll
  for (int mt = 0; mt < 2; mt++)
#pragma unroll
    for (int ks = 0; ks < 4; ks++) {
      const float4* p = (const float4*)(q + (size_t)s * (NH * DH) +
                                        (mt * 16 + l16) * DH + ks * 32 + quad * 8);
      float4 f0 = p[0], f1 = p[1];
      union { uint4 u; bf16x8 h; } cv;
      cv.u = (uint4){ pk_bf16(f0.x, f0.y), pk_bf16(f0.z, f0.w),
                      pk_bf16(f1.x, f1.y), pk_bf16(f1.z, f1.w) };
      afrag[mt][ks] = cv.h;
    }

  // ---- GEMM1: barrier-free, wave-private LDS staging, depth-2 reg prefetch ----
  uint4 kr0[4], kr1[4];
#pragma unroll
  for (int i = 0; i < 4; i++)
    kr0[i] = *(const uint4*)(kvb + (size_t)kidx[0] * 256 + quad * 32 + i * 8);
#pragma unroll
  for (int i = 0; i < 4; i++)
    kr1[i] = *(const uint4*)(kvb + (size_t)kidx[1] * 256 + quad * 32 + i * 8);

  floatx4 sc[4][2];
#pragma unroll
  for (int c = 0; c < 4; c++) {
    uint4* kcur = (c & 1) ? kr1 : kr0;
    LDS_FENCE();  // keep below writes after previous chunk's reads
    // stage chunk c into own slot (row l16) — same-wave DS is in-order
#pragma unroll
    for (int i = 0; i < 4; i++)
      *(uint4*)&kvw[l16 * KS_STRIDE + quad * 32 + i * 8] = kcur[i];
    if (c + 2 < 4) {  // refill buffer with chunk c+2
#pragma unroll
      for (int i = 0; i < 4; i++)
        kcur[i] = *(const uint4*)(kvb + (size_t)kidx[c + 2] * 256 + quad * 32 + i * 8);
    }
    LDS_FENCE();  // keep below reads after the staging writes
    bf16x8 bfr[4];
#pragma unroll
    for (int ks = 0; ks < 4; ks++)
      bfr[ks] = *(const bf16x8*)&kvw[l16 * KS_STRIDE + ks * 32 + quad * 8];
    floatx4 a0 = {0.f, 0.f, 0.f, 0.f};
    floatx4 a1 = {0.f, 0.f, 0.f, 0.f};
#pragma unroll
    for (int ks = 0; ks < 4; ks++) {
      a0 = __builtin_amdgcn_mfma_f32_16x16x32_bf16(afrag[0][ks], bfr[ks], a0, 0, 0, 0);
      a1 = __builtin_amdgcn_mfma_f32_16x16x32_bf16(afrag[1][ks], bfr[ks], a1, 0, 0, 0);
    }
    sc[c][0] = a0;
    sc[c][1] = a1;
  }

  // V prefetch (depth 2) — K slot reads all issued; global loads, no LDS hazard
  VR va = v_load_w(kvb, tkg, 0, wave, quad, l16);
  VR vb = v_load_w(kvb, tkg, 1, wave, quad, l16);

  // ---- softmax with sink ----
  float mh[2][4];
#pragma unroll
  for (int mt = 0; mt < 2; mt++)
#pragma unroll
    for (int r = 0; r < 4; r++) {
      float v = fmaxf(fmaxf(sc[0][mt][r], sc[1][mt][r]),
                      fmaxf(sc[2][mt][r], sc[3][mt][r]));
      RED16_MAX(v);
      mh[mt][r] = v;
    }
  if (l16 == 0) {
#pragma unroll
    for (int mt = 0; mt < 2; mt++)
#pragma unroll
      for (int r = 0; r < 4; r++)
        red[wave * 32 + mt * 16 + quad * 4 + r] = mh[mt][r];
  }
  __syncthreads();  // barrier 1: red + sink_s (also orders K reads vs V0 staging)
  v_write_w(kvw, va, quad, l16);                  // stage V0 into own slot
  va = v_load_w(kvb, tkg, 2, wave, quad, l16);    // prefetch V2
#pragma unroll
  for (int mt = 0; mt < 2; mt++)
#pragma unroll
    for (int r = 0; r < 4; r++) {
      int h = mt * 16 + quad * 4 + r;
      float v = red[h];
#pragma unroll
      for (int w = 1; w < 4; w++) v = fmaxf(v, red[w * 32 + h]);
      mh[mt][r] = fmaxf(v * QSC, sink_s[h]);  // exp2-domain max
    }
  float ps[2][4];
#pragma unroll
  for (int mt = 0; mt < 2; mt++)
#pragma unroll
    for (int r = 0; r < 4; r++) {
      float acc = 0.f;
#pragma unroll
      for (int c = 0; c < 4; c++) {
        float e = fast_exp2(fmaf(sc[c][mt][r], QSC, -mh[mt][r]));
        sc[c][mt][r] = e;
        acc += e;
      }
      RED16_SUM(acc);
      ps[mt][r] = acc;
    }
  if (l16 == 0) {
#pragma unroll
    for (int mt = 0; mt < 2; mt++)
#pragma unroll
      for (int r = 0; r < 4; r++)
        red2[wave * 32 + mt * 16 + quad * 4 + r] = ps[mt][r];
  }
  __syncthreads();  // barrier 2: red2
  float inv[2][4];
#pragma unroll
  for (int mt = 0; mt < 2; mt++)
#pragma unroll
    for (int r = 0; r < 4; r++) {
      int h = mt * 16 + quad * 4 + r;
      float dd = fast_exp2(sink_s[h] - mh[mt][r]);
#pragma unroll
      for (int w = 0; w < 4; w++) dd += red2[w * 32 + h];
      inv[mt][r] = 1.0f / dd;
    }
  // write P (bf16, unnormalized) to pbuf [head][col]
#pragma unroll
  for (int c = 0; c < 4; c++)
#pragma unroll
    for (int mt = 0; mt < 2; mt++) {
      int col = c * 64 + wave * 16 + l16;
      unsigned short* pb = &pbuf[(mt * 16 + quad * 4) * PB_STRIDE + col];
      unsigned p01 = pk_bf16(sc[c][mt][0], sc[c][mt][1]);
      unsigned p23 = pk_bf16(sc[c][mt][2], sc[c][mt][3]);
      pb[0] = (unsigned short)p01;
      pb[PB_STRIDE] = (unsigned short)(p01 >> 16);
      pb[2 * PB_STRIDE] = (unsigned short)p23;
      pb[3 * PB_STRIDE] = (unsigned short)(p23 >> 16);
    }
  __syncthreads();  // barrier 3: pbuf visible (V0 staging is wave-private)

  // ---- PV: barrier-free, wave-private V staging ----
  floatx4 oacc[2][2];
#pragma unroll
  for (int mt = 0; mt < 2; mt++)
#pragma unroll
    for (int nt = 0; nt < 2; nt++)
      oacc[mt][nt] = (floatx4){0.f, 0.f, 0.f, 0.f};

  pv_chunk(pbuf, kvw, 0, quad, l16, oacc);
  LDS_FENCE();                                    // c0 reads before V1 overwrite
  v_write_w(kvw, vb, quad, l16);                  // stage V1
  vb = v_load_w(kvb, tkg, 3, wave, quad, l16);    // prefetch V3
  LDS_FENCE();                                    // V1 writes before c1 reads

  pv_chunk(pbuf, kvw, 1, quad, l16, oacc);
  LDS_FENCE();
  v_write_w(kvw, va, quad, l16);                  // stage V2
  LDS_FENCE();

  pv_chunk(pbuf, kvw, 2, quad, l16, oacc);
  LDS_FENCE();
  v_write_w(kvw, vb, quad, l16);                  // stage V3
  LDS_FENCE();

  pv_chunk(pbuf, kvw, 3, quad, l16, oacc);

  // ---- epilogue ----
  {
    float* op = out + (size_t)s * (NH * DH);
#pragma unroll
    for (int mt = 0; mt < 2; mt++)
#pragma unroll
      for (int nt = 0; nt < 2; nt++)
#pragma unroll
        for (int r4 = 0; r4 < 4; r4++) {
          int h = mt * 16 + quad * 4 + r4;
          int d = wave * 32 + nt * 16 + l16;
          op[h * DH + d] = oacc[mt][nt][r4] * inv[mt][r4];
        }
  }
}

extern "C" void kernel_launch(void* const* d_in, const int* in_sizes, int n_in,
                              void* d_out, int out_size, void* d_ws, size_t ws_size,
                              hipStream_t stream) {
  (void)in_sizes; (void)n_in; (void)out_size; (void)ws_size;
  const float* q    = (const float*)d_in[0];
  const float* kv   = (const float*)d_in[1];
  const float* sink = (const float*)d_in[2];
  const int*   topk = (const int*)d_in[3];
  float* out = (float*)d_out;
  unsigned short* kvb = (unsigned short*)d_ws;  // 2 MB bf16 KV

  kv_to_bf16<<<dim3(1024), dim3(256), 0, stream>>>(kv, kvb);
  sparse_attn_kernel<<<dim3(SQ), dim3(256), 0, stream>>>(q, kvb, sink, topk, out);
}

// Round 8
// 129.412 us; speedup vs baseline: 1.2929x; 1.2929x over previous
//
#include <hip/hip_runtime.h>
#include <hip/hip_bf16.h>

#define SQ 2048
#define NH 32
#define DH 128
#define NK 256
#define SCALE 0.08838834764831845f
#define LOG2E 1.4426950408889634f

typedef __attribute__((ext_vector_type(8))) __bf16 bf16x8;
typedef __attribute__((ext_vector_type(4))) float floatx4;
typedef __attribute__((ext_vector_type(4))) unsigned uintx4;
typedef __attribute__((ext_vector_type(2))) unsigned uintx2;

// Scheduler-only fence: blocks MIR scheduler motion across this point but has
// NO memory-clobber semantics, so local arrays stay SROA'd in VGPRs.
// (R7's asm volatile memory clobber forced allocas to scratch -> 141MB spill traffic.)
#define SCHED_FENCE() __builtin_amdgcn_sched_barrier(0)

// element strides (u16)
#define KS_STRIDE 136   // K tile rows: 272B, 16B-aligned
#define VB_STRIDE 72    // V^T rows: 144B, 16B-aligned
#define PB_STRIDE 264
#define WSLOT 4608      // per-wave staging bytes: max(K 16*272=4352, V 32*144=4608)

// LDS: pbuf 16896 + 4*WSLOT 18432 + sink 128 + red 512 + red2 512 = 36480 -> 4 blocks/CU
#define OFF_KV   16896
#define OFF_SINK 35328
#define OFF_RED  35456
#define OFF_RED2 35968
#define SMEM_SZ  36480

__device__ __forceinline__ unsigned pk_bf16(float a, float b) {
  union { __hip_bfloat162 h2; unsigned u; } c;
  c.h2 = __float22bfloat162_rn(make_float2(a, b));
  return c.u;
}

__device__ __forceinline__ float fast_exp2(float x) {
#if __has_builtin(__builtin_amdgcn_exp2f)
  return __builtin_amdgcn_exp2f(x);
#else
  return exp2f(x);
#endif
}

template <int CTRL>
__device__ __forceinline__ float dpp_rot(float x) {
  int i = __builtin_bit_cast(int, x);
  i = __builtin_amdgcn_mov_dpp(i, CTRL, 0xF, 0xF, true);
  return __builtin_bit_cast(float, i);
}
#define RED16_MAX(v) { v = fmaxf(v, dpp_rot<0x121>(v)); v = fmaxf(v, dpp_rot<0x122>(v)); \
                       v = fmaxf(v, dpp_rot<0x124>(v)); v = fmaxf(v, dpp_rot<0x128>(v)); }
#define RED16_SUM(v) { v += dpp_rot<0x121>(v); v += dpp_rot<0x122>(v); \
                       v += dpp_rot<0x124>(v); v += dpp_rot<0x128>(v); }

// ---- pre-pass: kv fp32 [4096][2][128] -> bf16 in d_ws ----
__global__ __launch_bounds__(256) void kv_to_bf16(const float* __restrict__ kv,
                                                  unsigned short* __restrict__ kvb) {
  int i = blockIdx.x * 256 + threadIdx.x;  // float4 index, 262144 total
  float4 f = ((const float4*)kv)[i];
  uint2 o = { pk_bf16(f.x, f.y), pk_bf16(f.z, f.w) };
  ((uint2*)kvb)[i] = o;
}

struct VR { uintx4 a, b, c, d; };

// V gather, wave-private: lane (quad,l16) loads keys 4*l16..+3 of chunk c,
// d-range [wave*32+quad*8, +8) (16B contiguous)
__device__ __forceinline__ VR v_load_w(const unsigned short* __restrict__ kvb,
                                       const int* __restrict__ tkg, int c,
                                       int wave, int quad, int l16) {
  int4 i4 = *(const int4*)(tkg + c * 64 + 4 * l16);
  int off = 128 + wave * 32 + quad * 8;
  VR v;
  v.a = *(const uintx4*)(kvb + (size_t)i4.x * 256 + off);
  v.b = *(const uintx4*)(kvb + (size_t)i4.y * 256 + off);
  v.c = *(const uintx4*)(kvb + (size_t)i4.z * 256 + off);
  v.d = *(const uintx4*)(kvb + (size_t)i4.w * 256 + off);
  return v;
}

// transpose-pack to own slot: V^T[dloc][klocal], dloc = quad*8+..., klocal = 4*l16..+3
__device__ __forceinline__ void v_write_w(unsigned short* kvw, const VR& v,
                                          int quad, int l16) {
#pragma unroll
  for (int w = 0; w < 4; w++) {
    unsigned lo01 = __builtin_amdgcn_perm(v.b[w], v.a[w], 0x05040100u);
    unsigned lo23 = __builtin_amdgcn_perm(v.d[w], v.c[w], 0x05040100u);
    unsigned hi01 = __builtin_amdgcn_perm(v.b[w], v.a[w], 0x07060302u);
    unsigned hi23 = __builtin_amdgcn_perm(v.d[w], v.c[w], 0x07060302u);
    uintx2 lo = { lo01, lo23 }, hi = { hi01, hi23 };
    int dl = quad * 8 + 2 * w;
    *(uintx2*)&kvw[dl * VB_STRIDE + 4 * l16] = lo;
    *(uintx2*)&kvw[(dl + 1) * VB_STRIDE + 4 * l16] = hi;
  }
}

// PV chunk: A from pbuf (shared, behind syncthreads), B from own V^T slot
__device__ __forceinline__ void pv_chunk(const unsigned short* pbuf,
                                         const unsigned short* kvw, int c,
                                         int quad, int l16, floatx4 oacc[2][2]) {
#pragma unroll
  for (int ks = 0; ks < 2; ks++) {
    int kof = c * 64 + ks * 32 + quad * 8;
    bf16x8 a0 = *(const bf16x8*)&pbuf[l16 * PB_STRIDE + kof];
    bf16x8 a1 = *(const bf16x8*)&pbuf[(16 + l16) * PB_STRIDE + kof];
    int kl = ks * 32 + quad * 8;
    bf16x8 b0 = __builtin_bit_cast(bf16x8, *(const uintx4*)&kvw[l16 * VB_STRIDE + kl]);
    bf16x8 b1 = __builtin_bit_cast(bf16x8, *(const uintx4*)&kvw[(16 + l16) * VB_STRIDE + kl]);
    oacc[0][0] = __builtin_amdgcn_mfma_f32_16x16x32_bf16(a0, b0, oacc[0][0], 0, 0, 0);
    oacc[0][1] = __builtin_amdgcn_mfma_f32_16x16x32_bf16(a0, b1, oacc[0][1], 0, 0, 0);
    oacc[1][0] = __builtin_amdgcn_mfma_f32_16x16x32_bf16(a1, b0, oacc[1][0], 0, 0, 0);
    oacc[1][1] = __builtin_amdgcn_mfma_f32_16x16x32_bf16(a1, b1, oacc[1][1], 0, 0, 0);
  }
}

__global__ __launch_bounds__(256, 4) void sparse_attn_kernel(
    const float* __restrict__ q, const unsigned short* __restrict__ kvb,
    const float* __restrict__ sink, const int* __restrict__ topk,
    float* __restrict__ out) {
  __shared__ __align__(16) char smem[SMEM_SZ];
  unsigned short* pbuf = (unsigned short*)smem;
  float* sink_s = (float*)(smem + OFF_SINK);
  float* red    = (float*)(smem + OFF_RED);
  float* red2   = (float*)(smem + OFF_RED2);

  const int tid = threadIdx.x;
  const int s = blockIdx.x;
  const int wave = tid >> 6;
  const int lane = tid & 63;
  const int quad = lane >> 4;
  const int l16 = lane & 15;
  const int* tkg = topk + (size_t)s * NK;
  const float QSC = SCALE * LOG2E;
  unsigned short* kvw = (unsigned short*)(smem + OFF_KV + wave * WSLOT);  // own slot

  if (tid < 32) sink_s[tid] = sink[tid] * LOG2E;  // read only after red barrier

  // K row indices for this lane's n-rows (wave-private tile rows)
  int kidx[4];
#pragma unroll
  for (int c = 0; c < 4; c++) kidx[c] = tkg[c * 64 + wave * 16 + l16];

  // Q A-fragments direct from global (raw bf16; SCALE folded into softmax)
  bf16x8 afrag[2][4];
#pragma unroll
  for (int mt = 0; mt < 2; mt++)
#pragma unroll
    for (int ks = 0; ks < 4; ks++) {
      const float4* p = (const float4*)(q + (size_t)s * (NH * DH) +
                                        (mt * 16 + l16) * DH + ks * 32 + quad * 8);
      float4 f0 = p[0], f1 = p[1];
      union { uint4 u; bf16x8 h; } cv;
      cv.u = (uint4){ pk_bf16(f0.x, f0.y), pk_bf16(f0.z, f0.w),
                      pk_bf16(f1.x, f1.y), pk_bf16(f1.z, f1.w) };
      afrag[mt][ks] = cv.h;
    }

  // ---- GEMM1: barrier-free, wave-private LDS staging, depth-2 reg prefetch ----
  uintx4 kr0[4], kr1[4];
#pragma unroll
  for (int i = 0; i < 4; i++)
    kr0[i] = *(const uintx4*)(kvb + (size_t)kidx[0] * 256 + quad * 32 + i * 8);
#pragma unroll
  for (int i = 0; i < 4; i++)
    kr1[i] = *(const uintx4*)(kvb + (size_t)kidx[1] * 256 + quad * 32 + i * 8);

  floatx4 sc[4][2];
#pragma unroll
  for (int c = 0; c < 4; c++) {
    uintx4* kcur = (c & 1) ? kr1 : kr0;
    SCHED_FENCE();  // staging writes stay after previous chunk's reads
#pragma unroll
    for (int i = 0; i < 4; i++)
      *(uintx4*)&kvw[l16 * KS_STRIDE + quad * 32 + i * 8] = kcur[i];
    if (c + 2 < 4) {  // refill buffer with chunk c+2
#pragma unroll
      for (int i = 0; i < 4; i++)
        kcur[i] = *(const uintx4*)(kvb + (size_t)kidx[c + 2] * 256 + quad * 32 + i * 8);
    }
    SCHED_FENCE();  // fragment reads stay after the staging writes
    bf16x8 bfr[4];
#pragma unroll
    for (int ks = 0; ks < 4; ks++)
      bfr[ks] = __builtin_bit_cast(
          bf16x8, *(const uintx4*)&kvw[l16 * KS_STRIDE + ks * 32 + quad * 8]);
    floatx4 a0 = {0.f, 0.f, 0.f, 0.f};
    floatx4 a1 = {0.f, 0.f, 0.f, 0.f};
#pragma unroll
    for (int ks = 0; ks < 4; ks++) {
      a0 = __builtin_amdgcn_mfma_f32_16x16x32_bf16(afrag[0][ks], bfr[ks], a0, 0, 0, 0);
      a1 = __builtin_amdgcn_mfma_f32_16x16x32_bf16(afrag[1][ks], bfr[ks], a1, 0, 0, 0);
    }
    sc[c][0] = a0;
    sc[c][1] = a1;
  }

  // V prefetch (depth 2) — pure global loads, no LDS hazard
  VR va = v_load_w(kvb, tkg, 0, wave, quad, l16);
  VR vb = v_load_w(kvb, tkg, 1, wave, quad, l16);

  // ---- softmax with sink ----
  float mh[2][4];
#pragma unroll
  for (int mt = 0; mt < 2; mt++)
#pragma unroll
    for (int r = 0; r < 4; r++) {
      float v = fmaxf(fmaxf(sc[0][mt][r], sc[1][mt][r]),
                      fmaxf(sc[2][mt][r], sc[3][mt][r]));
      RED16_MAX(v);
      mh[mt][r] = v;
    }
  if (l16 == 0) {
#pragma unroll
    for (int mt = 0; mt < 2; mt++)
#pragma unroll
      for (int r = 0; r < 4; r++)
        red[wave * 32 + mt * 16 + quad * 4 + r] = mh[mt][r];
  }
  __syncthreads();  // barrier 1: red + sink_s; also orders K-slot reads vs V0 staging
  v_write_w(kvw, va, quad, l16);                  // stage V0 into own slot
  va = v_load_w(kvb, tkg, 2, wave, quad, l16);    // prefetch V2
#pragma unroll
  for (int mt = 0; mt < 2; mt++)
#pragma unroll
    for (int r = 0; r < 4; r++) {
      int h = mt * 16 + quad * 4 + r;
      float v = red[h];
#pragma unroll
      for (int w = 1; w < 4; w++) v = fmaxf(v, red[w * 32 + h]);
      mh[mt][r] = fmaxf(v * QSC, sink_s[h]);  // exp2-domain max
    }
  float ps[2][4];
#pragma unroll
  for (int mt = 0; mt < 2; mt++)
#pragma unroll
    for (int r = 0; r < 4; r++) {
      float acc = 0.f;
#pragma unroll
      for (int c = 0; c < 4; c++) {
        float e = fast_exp2(fmaf(sc[c][mt][r], QSC, -mh[mt][r]));
        sc[c][mt][r] = e;
        acc += e;
      }
      RED16_SUM(acc);
      ps[mt][r] = acc;
    }
  if (l16 == 0) {
#pragma unroll
    for (int mt = 0; mt < 2; mt++)
#pragma unroll
      for (int r = 0; r < 4; r++)
        red2[wave * 32 + mt * 16 + quad * 4 + r] = ps[mt][r];
  }
  __syncthreads();  // barrier 2: red2
  float inv[2][4];
#pragma unroll
  for (int mt = 0; mt < 2; mt++)
#pragma unroll
    for (int r = 0; r < 4; r++) {
      int h = mt * 16 + quad * 4 + r;
      float dd = fast_exp2(sink_s[h] - mh[mt][r]);
#pragma unroll
      for (int w = 0; w < 4; w++) dd += red2[w * 32 + h];
      inv[mt][r] = 1.0f / dd;
    }
  // write P (bf16, unnormalized) to pbuf [head][col]
#pragma unroll
  for (int c = 0; c < 4; c++)
#pragma unroll
    for (int mt = 0; mt < 2; mt++) {
      int col = c * 64 + wave * 16 + l16;
      unsigned short* pb = &pbuf[(mt * 16 + quad * 4) * PB_STRIDE + col];
      unsigned p01 = pk_bf16(sc[c][mt][0], sc[c][mt][1]);
      unsigned p23 = pk_bf16(sc[c][mt][2], sc[c][mt][3]);
      pb[0] = (unsigned short)p01;
      pb[PB_STRIDE] = (unsigned short)(p01 >> 16);
      pb[2 * PB_STRIDE] = (unsigned short)p23;
      pb[3 * PB_STRIDE] = (unsigned short)(p23 >> 16);
    }
  __syncthreads();  // barrier 3: pbuf + V0 (wave-private) visible

  // ---- PV: barrier-free, wave-private V staging ----
  floatx4 oacc[2][2];
#pragma unroll
  for (int mt = 0; mt < 2; mt++)
#pragma unroll
    for (int nt = 0; nt < 2; nt++)
      oacc[mt][nt] = (floatx4){0.f, 0.f, 0.f, 0.f};

  pv_chunk(pbuf, kvw, 0, quad, l16, oacc);
  SCHED_FENCE();                                  // c0 reads before V1 overwrite
  v_write_w(kvw, vb, quad, l16);                  // stage V1
  vb = v_load_w(kvb, tkg, 3, wave, quad, l16);    // prefetch V3
  SCHED_FENCE();                                  // V1 writes before c1 reads

  pv_chunk(pbuf, kvw, 1, quad, l16, oacc);
  SCHED_FENCE();
  v_write_w(kvw, va, quad, l16);                  // stage V2
  SCHED_FENCE();

  pv_chunk(pbuf, kvw, 2, quad, l16, oacc);
  SCHED_FENCE();
  v_write_w(kvw, vb, quad, l16);                  // stage V3
  SCHED_FENCE();

  pv_chunk(pbuf, kvw, 3, quad, l16, oacc);

  // ---- epilogue ----
  {
    float* op = out + (size_t)s * (NH * DH);
#pragma unroll
    for (int mt = 0; mt < 2; mt++)
#pragma unroll
      for (int nt = 0; nt < 2; nt++)
#pragma unroll
        for (int r4 = 0; r4 < 4; r4++) {
          int h = mt * 16 + quad * 4 + r4;
          int d = wave * 32 + nt * 16 + l16;
          op[h * DH + d] = oacc[mt][nt][r4] * inv[mt][r4];
        }
  }
}

extern "C" void kernel_launch(void* const* d_in, const int* in_sizes, int n_in,
                              void* d_out, int out_size, void* d_ws, size_t ws_size,
                              hipStream_t stream) {
  (void)in_sizes; (void)n_in; (void)out_size; (void)ws_size;
  const float* q    = (const float*)d_in[0];
  const float* kv   = (const float*)d_in[1];
  const float* sink = (const float*)d_in[2];
  const int*   topk = (const int*)d_in[3];
  float* out = (float*)d_out;
  unsigned short* kvb = (unsigned short*)d_ws;  // 2 MB bf16 KV

  kv_to_bf16<<<dim3(1024), dim3(256), 0, stream>>>(kv, kvb);
  sparse_attn_kernel<<<dim3(SQ), dim3(256), 0, stream>>>(q, kvb, sink, topk, out);
}